// Round 2
// baseline (289.128 us; speedup 1.0000x reference)
//
#include <hip/hip_runtime.h>
#include <hip/hip_bf16.h>

#define T_TOK 8192
#define DMODEL 1024
#define NEXP 128
#define CAP 256

typedef short s16x8 __attribute__((ext_vector_type(8)));
typedef float f32x4 __attribute__((ext_vector_type(4)));

__device__ __forceinline__ unsigned short f2bf(float f) {
    union { float f; unsigned int u; } v; v.f = f;
    unsigned int u = v.u;
    unsigned int r = (u + 0x7FFFu + ((u >> 16) & 1u)) >> 16;
    return (unsigned short)r;
}
__device__ __forceinline__ unsigned int pk2(unsigned short lo, unsigned short hi) {
    return (unsigned int)lo | ((unsigned int)hi << 16);
}

// ---------------- zero init: d_out and expert counters ----------------
__global__ __launch_bounds__(256) void zero_kernel(float* __restrict__ out, int n4, int* __restrict__ cnt) {
    int i = blockIdx.x * blockDim.x + threadIdx.x;
    if (i < NEXP) cnt[i] = 0;
    float4 z = make_float4(0.f, 0.f, 0.f, 0.f);
    float4* o4 = (float4*)out;
    for (int k = i; k < n4; k += gridDim.x * blockDim.x) o4[k] = z;
}

// ---------------- gating: fp64 logits, top-2, weights, dispatch lists, x->bf16 ----------------
// block = 256 threads, 32 tokens per block, grid = 256
__global__ __launch_bounds__(256) void gate_kernel(
    const float* __restrict__ x, const float* __restrict__ wg,
    unsigned short* __restrict__ xb, int* __restrict__ cnt,
    int* __restrict__ tokList, float* __restrict__ gateList)
{
    __shared__ float xs[32][36];     // [tok][k]
    __shared__ float wgs[32][128];   // [k][e]
    __shared__ double ls[128][33];   // [e][tok] logits fp64

    int tid = threadIdx.x;
    int tok0 = blockIdx.x * 32;

    int tg = tid >> 5;          // 0..7  token phase
    int eg = tid & 31;          // expert group (*4)
    int xtok = tid >> 3;        // 0..31 staging row
    int xoff = (tid & 7) * 4;   // staging col
    int wrow = tid >> 3;        // 0..31
    int wcol = (tid & 7) * 16;

    double acc[4][4];
    #pragma unroll
    for (int j = 0; j < 4; j++)
        #pragma unroll
        for (int i = 0; i < 4; i++) acc[j][i] = 0.0;

    for (int k0 = 0; k0 < DMODEL; k0 += 32) {
        // load to regs
        float4 xv = *(const float4*)(x + (size_t)(tok0 + xtok) * DMODEL + k0 + xoff);
        float4 wv4[4];
        #pragma unroll
        for (int c = 0; c < 4; c++)
            wv4[c] = *(const float4*)(wg + (size_t)(k0 + wrow) * NEXP + wcol + c * 4);

        __syncthreads();
        // stage LDS + write bf16 copy of x
        *(float4*)&xs[xtok][xoff] = xv;
        {
            uint2 o;
            o.x = pk2(f2bf(xv.x), f2bf(xv.y));
            o.y = pk2(f2bf(xv.z), f2bf(xv.w));
            *(uint2*)(xb + (size_t)(tok0 + xtok) * DMODEL + k0 + xoff) = o;
        }
        #pragma unroll
        for (int c = 0; c < 4; c++) *(float4*)&wgs[wrow][wcol + c * 4] = wv4[c];
        __syncthreads();

        #pragma unroll
        for (int k = 0; k < 32; k++) {
            float4 wv = *(const float4*)&wgs[k][eg * 4];
            #pragma unroll
            for (int j = 0; j < 4; j++) {
                float xf = xs[j * 8 + tg][k];
                double xd = (double)xf;
                acc[j][0] = fma(xd, (double)wv.x, acc[j][0]);
                acc[j][1] = fma(xd, (double)wv.y, acc[j][1]);
                acc[j][2] = fma(xd, (double)wv.z, acc[j][2]);
                acc[j][3] = fma(xd, (double)wv.w, acc[j][3]);
            }
        }
    }

    // write logits to LDS [e][tok]
    __syncthreads();
    #pragma unroll
    for (int j = 0; j < 4; j++)
        #pragma unroll
        for (int i = 0; i < 4; i++)
            ls[eg * 4 + i][j * 8 + tg] = acc[j][i];
    __syncthreads();

    if (tid < 32) {
        int tok = tid;
        double m1 = -1e300, m2 = -1e300;
        int i1 = 0, i2 = 0;
        #pragma unroll 4
        for (int e = 0; e < NEXP; e++) {
            double v = ls[e][tok];
            if (v > m1) { m2 = m1; i2 = i1; m1 = v; i1 = e; }
            else if (v > m2) { m2 = v; i2 = e; }
        }
        double ed = exp(m2 - m1);            // <= 1
        float g1 = (float)(1.0 / (1.0 + ed));
        float g2 = (float)(ed / (1.0 + ed));
        int gtok = tok0 + tok;
        int s1 = atomicAdd(&cnt[i1], 1);
        if (s1 < CAP) { tokList[i1 * CAP + s1] = gtok; gateList[i1 * CAP + s1] = g1; }
        int s2 = atomicAdd(&cnt[i2], 1);
        if (s2 < CAP) { tokList[i2 * CAP + s2] = gtok; gateList[i2 * CAP + s2] = g2; }
    }
}

// ---------------- grouped expert GEMM + weighted combine (atomics) ----------------
// grid = 128 experts * 8 n-blocks = 1024, block = 512 (8 waves)
// BM=256 (capacity), BN=128, BK=64.
#define LDS_STRIDE 72
__global__ __launch_bounds__(512) void moe_gemm(
    const float* __restrict__ we, const unsigned short* __restrict__ xb,
    const int* __restrict__ cnt, const int* __restrict__ tokList,
    const float* __restrict__ gateList, float* __restrict__ out)
{
    __shared__ unsigned short As[256 * LDS_STRIDE];  // 36 KB
    __shared__ unsigned short Bs[128 * LDS_STRIDE];  // 18 KB

    int b = blockIdx.x;
    int xcd = b & 7;
    int jj = b >> 3;
    int e = xcd * 16 + (jj >> 3);   // 8 n-blocks of one expert land on one XCD
    int nq = jj & 7;
    int nb = nq * 128;

    int count = cnt[e];
    if (count > CAP) count = CAP;

    int tid = threadIdx.x;
    int lane = tid & 63, wave = tid >> 6;
    int band = wave >> 1;   // 0..3 -> rows band*64..
    int nh = wave & 1;      // 0..1 -> cols nh*64..

    f32x4 acc[4][4] = {};

    // A staging: thread -> (row, half of 64 shorts). 32 shorts = 4 x uint4 each.
    int ar = tid >> 1, ah = tid & 1;
    int atok = -1;
    if (ar < count) atok = tokList[e * CAP + ar];
    const unsigned short* asrc = xb + ((size_t)(atok < 0 ? 0 : atok) << 10) + ah * 32;
    unsigned short* adst = As + ar * LDS_STRIDE + ah * 32;

    // B staging: thread -> (n, k-quarter of 16)
    int bn = tid & 127, bkq = tid >> 7;
    const float* bsrc = we + ((size_t)e << 20) + (size_t)(bkq * 16) * DMODEL + nb + bn;
    unsigned short* bdst = Bs + bn * LDS_STRIDE + bkq * 16;

    bool active = (band * 64) < count;

    for (int k0 = 0; k0 < DMODEL; k0 += 64) {
        // global loads to regs
        uint4 a0 = {0,0,0,0}, a1 = {0,0,0,0}, a2 = {0,0,0,0}, a3 = {0,0,0,0};
        if (atok >= 0) {
            const uint4* p = (const uint4*)(asrc + k0);
            a0 = p[0]; a1 = p[1]; a2 = p[2]; a3 = p[3];
        }
        float f[16];
        {
            const float* wp = bsrc + (size_t)k0 * DMODEL;
            #pragma unroll
            for (int i = 0; i < 16; i++) f[i] = wp[(size_t)i * DMODEL];
        }
        uint4 b0, b1;
        {
            unsigned short h[16];
            #pragma unroll
            for (int i = 0; i < 16; i++) h[i] = f2bf(f[i]);
            b0.x = pk2(h[0], h[1]);  b0.y = pk2(h[2], h[3]);
            b0.z = pk2(h[4], h[5]);  b0.w = pk2(h[6], h[7]);
            b1.x = pk2(h[8], h[9]);  b1.y = pk2(h[10], h[11]);
            b1.z = pk2(h[12], h[13]); b1.w = pk2(h[14], h[15]);
        }

        __syncthreads();   // previous iteration's LDS reads done
        *(uint4*)adst       = a0;
        *(uint4*)(adst + 8) = a1;
        *(uint4*)(adst + 16) = a2;
        *(uint4*)(adst + 24) = a3;
        *(uint4*)bdst       = b0;
        *(uint4*)(bdst + 8) = b1;
        __syncthreads();   // staging visible

        if (active) {
            #pragma unroll
            for (int kk = 0; kk < 64; kk += 32) {
                int kr = kk + ((lane >> 4) << 3);
                s16x8 af[4], bf[4];
                const unsigned short* abase = As + (size_t)(band * 64 + (lane & 15)) * LDS_STRIDE + kr;
                #pragma unroll
                for (int mf = 0; mf < 4; mf++)
                    af[mf] = *(const s16x8*)(abase + mf * 16 * LDS_STRIDE);
                const unsigned short* bbase = Bs + (size_t)(nh * 64 + (lane & 15)) * LDS_STRIDE + kr;
                #pragma unroll
                for (int nf = 0; nf < 4; nf++)
                    bf[nf] = *(const s16x8*)(bbase + nf * 16 * LDS_STRIDE);
                #pragma unroll
                for (int mf = 0; mf < 4; mf++)
                    #pragma unroll
                    for (int nf = 0; nf < 4; nf++)
                        acc[mf][nf] = __builtin_amdgcn_mfma_f32_16x16x32_bf16(af[mf], bf[nf], acc[mf][nf], 0, 0, 0);
            }
        }
    }

    // epilogue: weighted atomic combine into out
    if (active) {
        #pragma unroll
        for (int mf = 0; mf < 4; mf++) {
            #pragma unroll
            for (int j4 = 0; j4 < 4; j4++) {
                int r = band * 64 + mf * 16 + ((lane >> 4) << 2) + j4;
                if (r < count) {
                    int tok = tokList[e * CAP + r];
                    float g = gateList[e * CAP + r];
                    float* orow = out + ((size_t)tok << 10) + nb + nh * 64 + (lane & 15);
                    #pragma unroll
                    for (int nf = 0; nf < 4; nf++)
                        atomicAdd(orow + nf * 16, g * acc[mf][nf][j4]);
                }
            }
        }
    }
}

extern "C" void kernel_launch(void* const* d_in, const int* in_sizes, int n_in,
                              void* d_out, int out_size, void* d_ws, size_t ws_size,
                              hipStream_t stream) {
    const float* x  = (const float*)d_in[0];   // [4,2048,1024]
    const float* wg = (const float*)d_in[1];   // [1024,128]
    const float* we = (const float*)d_in[2];   // [128,1024,1024]
    float* out = (float*)d_out;                // [4,2048,1024]

    char* ws = (char*)d_ws;
    int* cnt        = (int*)ws;                        // 512 B
    int* tokList    = (int*)(ws + 1024);               // 128 KB
    float* gateList = (float*)(ws + 1024 + 131072);    // 128 KB
    unsigned short* xb = (unsigned short*)(ws + 524288); // 16 MB bf16 copy of x

    zero_kernel<<<2048, 256, 0, stream>>>(out, (T_TOK * DMODEL) / 4, cnt);
    gate_kernel<<<256, 256, 0, stream>>>(x, wg, xb, cnt, tokList, gateList);
    moe_gemm<<<1024, 512, 0, stream>>>(we, xb, cnt, tokList, gateList, out);
}